// Round 8
// baseline (153.025 us; speedup 1.0000x reference)
//
#include <hip/hip_runtime.h>

#define IN_NUM 1152
#define OUT_NUM 10
#define OUT_DIM 16
#define IN_DIM 8
#define NB 256
#define KTOT 9216

// workspace float offsets
#define OFF_SPART 0
#define SZ_SPART (96 * OUT_NUM * OUT_DIM * NB)        // 3,932,160
#define OFF_BP (OFF_SPART + SZ_SPART)
#define SZ_BP (32 * IN_NUM * OUT_NUM)                 // 368,640 (4 b-quarters x 8 c)
#define OFF_WT (OFF_BP + SZ_BP)
#define SZ_WT (OUT_NUM * OUT_DIM * IN_DIM * IN_NUM)   // 1,474,560

#define SMEM_FLOATS 5792   // 23,168 B per block (p1)

// ---- phase 1: spart[isp][j][d][b] = sum_{k in chunk} c[i,j]W[i,j,d,c] * x[b][k] ----
// 128 threads: 64 bb (x4 b via float4) x 2 dg (x8 d).
// At it==0 additionally materializes Wt[j][d][c][i] (raw W transpose) for k_pB.
__device__ __forceinline__ void phase1(float* smem, int t, int w, int it,
                                       const float* __restrict__ x, const float* __restrict__ W,
                                       float* __restrict__ Wt,
                                       const float* __restrict__ bp, float* __restrict__ spart) {
    int g8 = w / 80, r = w - g8 * 80;
    int j = r >> 3, isp = g8 * 8 + (r & 7);   // same-isp blocks 8 apart -> same XCD
    int cch = isp / 12;
    int i0 = (isp - cch * 12) * 96;
    int k0 = isp * 96;
    float (*xt)[260] = (float (*)[260])smem;           // 16 x 260 = 4160
    float (*at)[16]  = (float (*)[16])(smem + 4160);   // 96 x 16 = 1536
    float* ldc = smem + 5696;                          // 96
    if (t < 96) {
        float cv;
        if (it == 0) {
            cv = 0.1f;
        } else {
            int i = i0 + t;
            float bt_[OUT_NUM];
#pragma unroll
            for (int jp = 0; jp < OUT_NUM; ++jp) bt_[jp] = 0.f;
#pragma unroll
            for (int row = 0; row < 32; ++row) {   // 4 quarters x 8 c partial rows
                const float* p = &bp[((size_t)row * IN_NUM + i) * OUT_NUM];
#pragma unroll
                for (int jp = 0; jp < OUT_NUM; ++jp) bt_[jp] += p[jp];
            }
            float m = -1e30f;
#pragma unroll
            for (int jp = 0; jp < OUT_NUM; ++jp) { bt_[jp] *= (1.f / NB); m = fmaxf(m, bt_[jp]); }
            float s = 0.f;
#pragma unroll
            for (int jp = 0; jp < OUT_NUM; ++jp) { bt_[jp] = __expf(bt_[jp] - m); s += bt_[jp]; }
            cv = bt_[j] / s;
        }
        ldc[t] = cv;
    }
    __syncthreads();
    if (it == 0) {
        for (int e = t; e < 1536; e += 128) {
            int d = e / 96, kk = e - d * 96;
            float raw = W[(size_t)(i0 + kk) * 1280 + j * 128 + d * 8 + cch];
            Wt[(size_t)(j * 16 + d) * KTOT + cch * IN_NUM + i0 + kk] = raw;
            at[kk][d] = 0.1f * raw;
        }
    } else {
        for (int e = t; e < 1536; e += 128) {
            int d = e / 96, kk = e - d * 96;
            at[kk][d] = ldc[kk] * Wt[(size_t)(j * 16 + d) * KTOT + cch * IN_NUM + i0 + kk];
        }
    }
    int bb = t & 63, dg = t >> 6;
    int q4 = t & 3, row = t >> 2;
    float acc[32];
#pragma unroll
    for (int q = 0; q < 32; ++q) acc[q] = 0.f;
    for (int ch = 0; ch < 6; ++ch) {
        __syncthreads();
#pragma unroll
        for (int rr = 0; rr < 8; ++rr) {
            int b = rr * 32 + row;
            float4 xv = *reinterpret_cast<const float4*>(
                &x[(size_t)b * KTOT + k0 + ch * 16 + q4 * 4]);
            xt[q4 * 4 + 0][b] = xv.x; xt[q4 * 4 + 1][b] = xv.y;
            xt[q4 * 4 + 2][b] = xv.z; xt[q4 * 4 + 3][b] = xv.w;
        }
        __syncthreads();
#pragma unroll
        for (int kk = 0; kk < 16; ++kk) {
            float4 xv = *reinterpret_cast<const float4*>(&xt[kk][bb * 4]);
            float4 a0 = *reinterpret_cast<const float4*>(&at[ch * 16 + kk][dg * 8]);      // uniform -> broadcast
            float4 a1 = *reinterpret_cast<const float4*>(&at[ch * 16 + kk][dg * 8 + 4]);  // uniform -> broadcast
            acc[0]  += a0.x * xv.x; acc[1]  += a0.x * xv.y; acc[2]  += a0.x * xv.z; acc[3]  += a0.x * xv.w;
            acc[4]  += a0.y * xv.x; acc[5]  += a0.y * xv.y; acc[6]  += a0.y * xv.z; acc[7]  += a0.y * xv.w;
            acc[8]  += a0.z * xv.x; acc[9]  += a0.z * xv.y; acc[10] += a0.z * xv.z; acc[11] += a0.z * xv.w;
            acc[12] += a0.w * xv.x; acc[13] += a0.w * xv.y; acc[14] += a0.w * xv.z; acc[15] += a0.w * xv.w;
            acc[16] += a1.x * xv.x; acc[17] += a1.x * xv.y; acc[18] += a1.x * xv.z; acc[19] += a1.x * xv.w;
            acc[20] += a1.y * xv.x; acc[21] += a1.y * xv.y; acc[22] += a1.y * xv.z; acc[23] += a1.y * xv.w;
            acc[24] += a1.z * xv.x; acc[25] += a1.z * xv.y; acc[26] += a1.z * xv.z; acc[27] += a1.z * xv.w;
            acc[28] += a1.w * xv.x; acc[29] += a1.w * xv.y; acc[30] += a1.w * xv.z; acc[31] += a1.w * xv.w;
        }
    }
    float* sp = spart + (size_t)(isp * OUT_NUM + j) * (OUT_DIM * NB);
#pragma unroll
    for (int dd = 0; dd < 8; ++dd) {
        float4 o;
        o.x = acc[dd * 4 + 0]; o.y = acc[dd * 4 + 1];
        o.z = acc[dd * 4 + 2]; o.w = acc[dd * 4 + 3];
        *reinterpret_cast<float4*>(&sp[(dg * 8 + dd) * NB + bb * 4]) = o;
    }
}

// ---- phase 2 (final only): reduce spart over isp, squash, write out[b][j][d] ----
__device__ __forceinline__ void phase2(float* smem, int t, int w,
                                       const float* __restrict__ spart, float* __restrict__ dst) {
    float (*red)[32][17] = (float (*)[32][17])smem;    // 4352
    float (*nrm)[9] = (float (*)[9])(smem + 4352);     // 288
    float* cf = smem + 4640;                           // 32
    int j = w >> 3, bt2 = w & 7;
    int ie = t >> 5, bb = t & 31;
    int b = bt2 * 32 + bb;
    float acc[16];
#pragma unroll
    for (int d = 0; d < 16; ++d) acc[d] = 0.f;
    for (int q = 0; q < 12; ++q) {
        int isp = ie * 12 + q;
        const float* sp = spart + (size_t)(isp * OUT_NUM + j) * (OUT_DIM * NB) + b;
#pragma unroll
        for (int d = 0; d < 16; ++d) acc[d] += sp[d * NB];
    }
#pragma unroll
    for (int d = 0; d < 16; ++d) red[ie][bb][d] = acc[d];
    __syncthreads();
    int bb2 = t >> 3, dp = t & 7;
    float s0 = 0.f, s1 = 0.f;
#pragma unroll
    for (int e = 0; e < 8; ++e) { s0 += red[e][bb2][dp * 2]; s1 += red[e][bb2][dp * 2 + 1]; }
    nrm[bb2][dp] = s0 * s0 + s1 * s1;
    __syncthreads();
    if (t < 32) {
        float qn = 0.f;
#pragma unroll
        for (int d = 0; d < 8; ++d) qn += nrm[t][d];
        cf[t] = qn / ((1.f + qn) * sqrtf(qn));
    }
    __syncthreads();
    float cs = cf[bb2];
    float* o = dst + (size_t)(bt2 * 32 + bb2) * (OUT_NUM * OUT_DIM) + j * OUT_DIM + dp * 2;
    o[0] = s0 * cs;
    o[1] = s1 * cs;
}

// ---- fused squash + b-update: per (j, bq, ks) block ----
// A: s[j,d,b] = sum_isp spart (64 b's), squash -> v in LDS
// B: bp[bq*8+c][i][j] (+)= sum_d Wt[j,d,k] * sum_b v[b,d]*x[b,k], k in ks-slice of 1536
__global__ __launch_bounds__(256) void k_pB(const float* __restrict__ x,
                                            float* __restrict__ ws, int it) {
    __shared__ float vlds[64][20];   // 16B-aligned rows -> uniform b128 broadcast reads
    __shared__ float sq[4][64];
    __shared__ float cf[64];
    const float* spart = ws + OFF_SPART;
    const float* Wt = ws + OFF_WT;
    float* bp = ws + OFF_BP;
    int u = blockIdx.x, t = threadIdx.x;
    int g = u / 80, r = u - g * 80;
    int j = r >> 3, e = r & 7, m = g * 8 + e;   // same (bq,ks) j-group -> same XCD
    int bq = m / 6, ks = m - bq * 6;
    int dq = t >> 6, bb = t & 63;

    // A: reduce spart over isp for (j, bq*64+bb, d=dq*4..dq*4+3)
    float sacc[4] = {0.f, 0.f, 0.f, 0.f};
    const float* spb = spart + ((size_t)j * OUT_DIM + dq * 4) * NB + bq * 64 + bb;
#pragma unroll 4
    for (int isp = 0; isp < 96; ++isp) {
        const float* sp = spb + (size_t)isp * (OUT_NUM * OUT_DIM * NB);
        sacc[0] += sp[0]; sacc[1] += sp[NB]; sacc[2] += sp[2 * NB]; sacc[3] += sp[3 * NB];
    }
    sq[dq][bb] = sacc[0] * sacc[0] + sacc[1] * sacc[1] + sacc[2] * sacc[2] + sacc[3] * sacc[3];
#pragma unroll
    for (int dd = 0; dd < 4; ++dd) vlds[bb][dq * 4 + dd] = sacc[dd];
    __syncthreads();
    if (t < 64) {
        float qn = sq[0][t] + sq[1][t] + sq[2][t] + sq[3][t];
        cf[t] = qn / ((1.f + qn) * sqrtf(qn));
    }
    __syncthreads();
    {
        float c_ = cf[bb];
#pragma unroll
        for (int dd = 0; dd < 4; ++dd) vlds[bb][dq * 4 + dd] = sacc[dd] * c_;
    }
    __syncthreads();

    // B: bp update for k = ks*1536 + kt*256 + t
    int kbase = ks * 1536 + t;
    float wt[6][16];
#pragma unroll
    for (int kt = 0; kt < 6; ++kt) {
        int k = kbase + kt * 256;
#pragma unroll
        for (int d = 0; d < 16; ++d)
            wt[kt][d] = Wt[(size_t)(j * OUT_DIM + d) * KTOT + k];
    }
    float bs[6] = {0.f, 0.f, 0.f, 0.f, 0.f, 0.f};
    const float* xb = x + (size_t)(bq * 64) * KTOT + kbase;
#pragma unroll 2
    for (int b = 0; b < 64; ++b) {
        float4 v0 = *reinterpret_cast<const float4*>(&vlds[b][0]);    // uniform -> broadcast
        float4 v1 = *reinterpret_cast<const float4*>(&vlds[b][4]);
        float4 v2 = *reinterpret_cast<const float4*>(&vlds[b][8]);
        float4 v3 = *reinterpret_cast<const float4*>(&vlds[b][12]);
        const float* xrow = xb + (size_t)b * KTOT;
#pragma unroll
        for (int kt = 0; kt < 6; ++kt) {
            float dot = wt[kt][0] * v0.x + wt[kt][1] * v0.y + wt[kt][2] * v0.z + wt[kt][3] * v0.w
                      + wt[kt][4] * v1.x + wt[kt][5] * v1.y + wt[kt][6] * v1.z + wt[kt][7] * v1.w
                      + wt[kt][8] * v2.x + wt[kt][9] * v2.y + wt[kt][10] * v2.z + wt[kt][11] * v2.w
                      + wt[kt][12] * v3.x + wt[kt][13] * v3.y + wt[kt][14] * v3.z + wt[kt][15] * v3.w;
            bs[kt] += xrow[kt * 256] * dot;
        }
    }
#pragma unroll
    for (int kt = 0; kt < 6; ++kt) {
        int k = kbase + kt * 256;
        int c = k / IN_NUM, i = k - c * IN_NUM;
        size_t idx = (size_t)(bq * 8 + c) * (IN_NUM * OUT_NUM) + (size_t)i * OUT_NUM + j;
        float prev = (it == 0) ? 0.f : bp[idx];
        bp[idx] = prev + bs[kt];
    }
}

// ================= kernels =================
__global__ __launch_bounds__(128, 4) void k_p1(const float* __restrict__ x, const float* __restrict__ W,
                                               float* __restrict__ ws, int it) {
    __shared__ float smem[SMEM_FLOATS];
    phase1(smem, threadIdx.x, blockIdx.x, it, x, W, ws + OFF_WT, ws + OFF_BP, ws + OFF_SPART);
}
__global__ __launch_bounds__(256, 4) void k_p2(const float* __restrict__ ws, float* __restrict__ dst) {
    __shared__ float smem[SMEM_FLOATS];
    phase2(smem, threadIdx.x, blockIdx.x, ws + OFF_SPART, dst);
}

extern "C" void kernel_launch(void* const* d_in, const int* in_sizes, int n_in,
                              void* d_out, int out_size, void* d_ws, size_t ws_size,
                              hipStream_t stream) {
    const float* x = (const float*)d_in[0];   // [256][8][1152]
    const float* W = (const float*)d_in[1];   // [1152][10][16][8]
    float* out = (float*)d_out;               // [256][10][16][1]
    float* ws = (float*)d_ws;

    for (int it = 0; it < 3; ++it) {
        k_p1<<<dim3(960), dim3(128), 0, stream>>>(x, W, ws, it);
        if (it < 2)
            k_pB<<<dim3(240), dim3(256), 0, stream>>>(x, ws, it);
        else
            k_p2<<<dim3(80), dim3(256), 0, stream>>>(ws, out);
    }
}

// Round 9
// 123.001 us; speedup vs baseline: 1.2441x; 1.2441x over previous
//
#include <hip/hip_runtime.h>

#define IN_NUM 1152
#define OUT_NUM 10
#define OUT_DIM 16
#define IN_DIM 8
#define NB 256
#define KTOT 9216

// workspace float offsets
#define OFF_SPART 0
#define SZ_SPART (96 * OUT_NUM * OUT_DIM * NB)        // 3,932,160
#define OFF_BP (OFF_SPART + SZ_SPART)
#define SZ_BP (32 * IN_NUM * OUT_NUM)                 // 368,640 (4 b-quarters x 8 c)
#define OFF_VT (OFF_BP + SZ_BP)
#define SZ_VT (NB * OUT_NUM * OUT_DIM)                // 40,960
#define OFF_WT (OFF_VT + SZ_VT)
#define SZ_WT (OUT_NUM * OUT_DIM * KTOT)              // 1,474,560  Wt[j][d][k]
#define OFF_WT2 (OFF_WT + SZ_WT)
#define SZ_WT2 (OUT_NUM * KTOT * OUT_DIM)             // 1,474,560  Wt2[j][k][d]
#define OFF_XT (OFF_WT2 + SZ_WT2)
#define SZ_XT (KTOT * NB)                             // 2,359,296  xT[k][b]
// total ~38.5 MB (ws is ~268 MB per harness fill size)

// ---- prep: xT[k][b] = x[b][k];  Wt[j][d*8+c][i] and Wt2[j][c*1152+i][d] = W[i][j][d][c] ----
__global__ __launch_bounds__(256) void k_prep(const float* __restrict__ x,
                                              const float* __restrict__ W,
                                              float* __restrict__ ws) {
    __shared__ float smem[64 * 68];
    float* xT = ws + OFF_XT;
    float* Wt = ws + OFF_WT;
    float* Wt2 = ws + OFF_WT2;
    int u = blockIdx.x, t = threadIdx.x;
    if (u < 576) {
        // x transpose, tile 64b x 64k
        float (*lds)[68] = (float (*)[68])smem;
        int kt = u % 144, bt = u / 144;
        int k0 = kt * 64, b0 = bt * 64;
        int r = t >> 4, c4 = (t & 15) * 4;
#pragma unroll
        for (int p = 0; p < 4; ++p) {
            int bb = p * 16 + r;
            float4 v = *reinterpret_cast<const float4*>(&x[(size_t)(b0 + bb) * KTOT + k0 + c4]);
            lds[bb][c4 + 0] = v.x; lds[bb][c4 + 1] = v.y;
            lds[bb][c4 + 2] = v.z; lds[bb][c4 + 3] = v.w;
        }
        __syncthreads();
#pragma unroll
        for (int p = 0; p < 4; ++p) {
            int kk = p * 16 + r;
            float4 o;
            o.x = lds[c4 + 0][kk]; o.y = lds[c4 + 1][kk];
            o.z = lds[c4 + 2][kk]; o.w = lds[c4 + 3][kk];
            *reinterpret_cast<float4*>(&xT[(size_t)(k0 + kk) * NB + b0 + c4]) = o;
        }
    } else {
        // W transpose, tile 32 i-rows x 128 (j-slice)
        float (*lds2)[129] = (float (*)[129])smem;
        int w = u - 576;
        int itile = w / 10, j = w - itile * 10;
        int i0 = itile * 32;
        int r0 = t >> 5, c4b = t & 31;
#pragma unroll
        for (int rr = 0; rr < 4; ++rr) {
            int rrow = rr * 8 + r0;
            float4 w4 = *reinterpret_cast<const float4*>(
                &W[(size_t)(i0 + rrow) * 1280 + j * 128 + c4b * 4]);
            lds2[rrow][c4b * 4 + 0] = w4.x; lds2[rrow][c4b * 4 + 1] = w4.y;
            lds2[rrow][c4b * 4 + 2] = w4.z; lds2[rrow][c4b * 4 + 3] = w4.w;
        }
        __syncthreads();
        // Wt[j][dc][i]
        int ii = t & 31, dcq = t >> 5;
#pragma unroll
        for (int rr = 0; rr < 16; ++rr) {
            int dc = rr * 8 + dcq;
            Wt[(size_t)(j * 128 + dc) * IN_NUM + i0 + ii] = lds2[ii][dc];
        }
        // Wt2[j][c*1152+i][d], fully-coalesced float4 stores (d4 lane-minor)
        int d4 = t & 3, ii2 = (t >> 2) & 31, ch0 = t >> 7;   // ch0 in {0,1}
#pragma unroll
        for (int c2 = 0; c2 < 4; ++c2) {
            int c = c2 * 2 + ch0;
            float4 o;
            o.x = lds2[ii2][(d4 * 4 + 0) * 8 + c];
            o.y = lds2[ii2][(d4 * 4 + 1) * 8 + c];
            o.z = lds2[ii2][(d4 * 4 + 2) * 8 + c];
            o.w = lds2[ii2][(d4 * 4 + 3) * 8 + c];
            *reinterpret_cast<float4*>(
                &Wt2[((size_t)j * KTOT + c * IN_NUM + i0 + ii2) * OUT_DIM + d4 * 4]) = o;
        }
    }
}

// ---- p1: spart[isp][j][d][b] = sum_kk (ldc[kk]*Wt2[j][k][d]) * xT[k][b] ----
// thread = one b; x from global (coalesced, L2); A via block-uniform s_load_dwordx16; no LDS in loop.
__global__ __launch_bounds__(256, 4) void k_p1(float* __restrict__ ws, int it) {
    __shared__ float ldc[96];
    const float* xT = ws + OFF_XT;
    const float* Wt2 = ws + OFF_WT2;
    const float* bp = ws + OFF_BP;
    float* spart = ws + OFF_SPART;
    int w = blockIdx.x, t = threadIdx.x;
    int g8 = w / 80, r = w - g8 * 80;
    int j = r >> 3, isp = g8 * 8 + (r & 7);   // same-isp j-group 8 apart -> same XCD
    int cch = isp / 12;
    int i0 = (isp - cch * 12) * 96;
    int k0 = isp * 96;
    if (t < 96) {
        float cv;
        if (it == 0) {
            cv = 0.1f;
        } else {
            int i = i0 + t;
            float bt_[OUT_NUM];
#pragma unroll
            for (int jp = 0; jp < OUT_NUM; ++jp) bt_[jp] = 0.f;
#pragma unroll 4
            for (int row = 0; row < 32; ++row) {
                const float2* p2 = reinterpret_cast<const float2*>(
                    &bp[(size_t)row * (IN_NUM * OUT_NUM) + i * OUT_NUM]);
#pragma unroll
                for (int q = 0; q < 5; ++q) {
                    float2 v = p2[q];
                    bt_[q * 2] += v.x; bt_[q * 2 + 1] += v.y;
                }
            }
            float m = -1e30f;
#pragma unroll
            for (int jp = 0; jp < OUT_NUM; ++jp) { bt_[jp] *= (1.f / NB); m = fmaxf(m, bt_[jp]); }
            float s = 0.f;
#pragma unroll
            for (int jp = 0; jp < OUT_NUM; ++jp) { bt_[jp] = __expf(bt_[jp] - m); s += bt_[jp]; }
            cv = bt_[j] / s;
        }
        ldc[t] = cv;
    }
    __syncthreads();
    const float* xp = xT + (size_t)k0 * NB + t;                  // b = t
    const float* wp = Wt2 + ((size_t)j * KTOT + k0) * OUT_DIM;   // block-uniform
    float acc[16];
#pragma unroll
    for (int d = 0; d < 16; ++d) acc[d] = 0.f;
#pragma unroll 4
    for (int kk = 0; kk < 96; ++kk) {
        float xv = xp[(size_t)kk * NB];
        float xs = xv * ldc[kk];                                 // uniform LDS broadcast
        const float* a = wp + kk * OUT_DIM;                      // -> s_load_dwordx16
#pragma unroll
        for (int d = 0; d < 16; ++d) acc[d] += a[d] * xs;        // v_fmac v, s, v
    }
    float* sp = spart + ((size_t)isp * OUT_NUM + j) * (OUT_DIM * NB) + t;
#pragma unroll
    for (int d = 0; d < 16; ++d) sp[d * NB] = acc[d];
}

// ---- p2: reduce spart over isp, squash, write dst[b][j][d] ----
__global__ __launch_bounds__(256, 4) void k_p2(const float* __restrict__ ws, float* __restrict__ dst) {
    __shared__ float smem[4672];
    float (*red)[32][17] = (float (*)[32][17])smem;    // 4352
    float (*nrm)[9] = (float (*)[9])(smem + 4352);     // 288
    float* cf = smem + 4640;                           // 32
    const float* spart = ws + OFF_SPART;
    int wvar = blockIdx.x, t = threadIdx.x;
    int j = wvar >> 3, bt2 = wvar & 7;
    int ie = t >> 5, bb = t & 31;
    int b = bt2 * 32 + bb;
    float acc[16];
#pragma unroll
    for (int d = 0; d < 16; ++d) acc[d] = 0.f;
    for (int q = 0; q < 12; ++q) {
        int isp = ie * 12 + q;
        const float* sp = spart + (size_t)(isp * OUT_NUM + j) * (OUT_DIM * NB) + b;
#pragma unroll
        for (int d = 0; d < 16; ++d) acc[d] += sp[d * NB];
    }
#pragma unroll
    for (int d = 0; d < 16; ++d) red[ie][bb][d] = acc[d];
    __syncthreads();
    int bb2 = t >> 3, dp = t & 7;
    float s0 = 0.f, s1 = 0.f;
#pragma unroll
    for (int e = 0; e < 8; ++e) { s0 += red[e][bb2][dp * 2]; s1 += red[e][bb2][dp * 2 + 1]; }
    nrm[bb2][dp] = s0 * s0 + s1 * s1;
    __syncthreads();
    if (t < 32) {
        float qn = 0.f;
#pragma unroll
        for (int d = 0; d < 8; ++d) qn += nrm[t][d];
        cf[t] = qn / ((1.f + qn) * sqrtf(qn));
    }
    __syncthreads();
    float cs = cf[bb2];
    float* o = dst + (size_t)(bt2 * 32 + bb2) * (OUT_NUM * OUT_DIM) + j * OUT_DIM + dp * 2;
    o[0] = s0 * cs;
    o[1] = s1 * cs;
}

// ---- p3: bp[bq*8+c][i][j] = prev + sum_d Wt[j][d][k] * sum_{b in quarter} vt[b][j][d]*x[b][k] ----
__global__ __launch_bounds__(256) void k_p3(const float* __restrict__ x,
                                            float* __restrict__ ws, int it) {
    const float* vt = ws + OFF_VT;
    const float* Wt = ws + OFF_WT;
    float* bp = ws + OFF_BP;
    int u = blockIdx.x, t = threadIdx.x;
    int kt = u % 36;
    int jq = u / 36;
    int j = jq >> 2, bq = jq & 3;
    int k = kt * 256 + t;
    int c = k / IN_NUM, i = k - c * IN_NUM;
    const float* xk = x + k + (size_t)(bq * 64) * KTOT;
    const float* vjb = vt + (size_t)(bq * 64) * (OUT_NUM * OUT_DIM) + j * OUT_DIM;
    float macc[16];
#pragma unroll
    for (int d = 0; d < 16; ++d) macc[d] = 0.f;
#pragma unroll 8
    for (int b = 0; b < 64; ++b) {
        float xv = xk[(size_t)b * KTOT];
        const float* vb = vjb + (size_t)b * (OUT_NUM * OUT_DIM);   // block-uniform -> s_load
#pragma unroll
        for (int d = 0; d < 16; ++d) macc[d] += vb[d] * xv;
    }
    float bs = 0.f;
#pragma unroll
    for (int d = 0; d < 16; ++d)
        bs += macc[d] * Wt[(size_t)(j * OUT_DIM + d) * KTOT + k];
    size_t idx = (size_t)(bq * 8 + c) * (IN_NUM * OUT_NUM) + (size_t)i * OUT_NUM + j;
    float prev = (it == 0) ? 0.f : bp[idx];
    bp[idx] = prev + bs;
}

extern "C" void kernel_launch(void* const* d_in, const int* in_sizes, int n_in,
                              void* d_out, int out_size, void* d_ws, size_t ws_size,
                              hipStream_t stream) {
    const float* x = (const float*)d_in[0];   // [256][8][1152]
    const float* W = (const float*)d_in[1];   // [1152][10][16][8]
    float* out = (float*)d_out;               // [256][10][16][1]
    float* ws = (float*)d_ws;

    k_prep<<<dim3(936), dim3(256), 0, stream>>>(x, W, ws);
    for (int it = 0; it < 3; ++it) {
        k_p1<<<dim3(960), dim3(256), 0, stream>>>(ws, it);
        k_p2<<<dim3(80), dim3(256), 0, stream>>>(ws, it == 2 ? out : (ws + OFF_VT));
        if (it < 2) k_p3<<<dim3(1440), dim3(256), 0, stream>>>(x, ws, it);
    }
}